// Round 4
// baseline (5731.889 us; speedup 1.0000x reference)
//
#include <hip/hip_runtime.h>

// ---- problem constants ----
constexpr int NT   = 2048;   // tokens
constexpr int HD   = 512;    // hidden = HQ*D = HKV*D
constexpr int MBLK = 4096;   // 16^3 compression block slots
constexpr int SBLK = 512;    // 8^3 selection block slots
constexpr int NW3  = 729;    // 9^3 shifted windows
constexpr int KPAD = 2048;   // padded key stride for ckT4
#define NEGI (-1e30f)

// =========================================================================
// token prep: coords decode, ids, bucket counts
// =========================================================================
__global__ __launch_bounds__(256) void token_prep(
    const int* __restrict__ cf, int* __restrict__ bid, int* __restrict__ sbid,
    int* __restrict__ wid, int* __restrict__ ibid, int* __restrict__ cnt,
    int* __restrict__ selcnt, int* __restrict__ wincnt) {
  int n = blockIdx.x * 256 + threadIdx.x;
  if (n >= NT) return;
  int c = cf[n];
  int x = c >> 12, y = (c >> 6) & 63, z = c & 63;
  int b  = ((x >> 2) << 8) | ((y >> 2) << 4) | (z >> 2);
  int sb = ((x >> 3) << 6) | ((y >> 3) << 3) | (z >> 3);
  int w  = ((x + 4) >> 3) * 81 + ((y + 4) >> 3) * 9 + ((z + 4) >> 3);
  int ib = ((x & 3) << 4) | ((y & 3) << 2) | (z & 3);
  bid[n] = b; sbid[n] = sb; wid[n] = w; ibid[n] = ib;
  atomicAdd(&cnt[b], 1);
  atomicAdd(&selcnt[sb], 1);
  atomicAdd(&wincnt[w], 1);
}

// =========================================================================
// single-block scans: occupied-block compaction + bucket offsets
// =========================================================================
__global__ __launch_bounds__(1024) void scan_all(
    const int* __restrict__ cnt, int* __restrict__ occ_m, int* __restrict__ inv,
    int* __restrict__ noccPtr,
    const int* __restrict__ selcnt, int* __restrict__ seloff, int* __restrict__ selpos,
    const int* __restrict__ wincnt, int* __restrict__ winoff, int* __restrict__ winpos) {
  __shared__ int buf[1024];
  int t = threadIdx.x;

  // ---- phase 1: compaction scan over MBLK=4096 (4 per thread) ----
  int base = t * 4;
  int f0 = cnt[base + 0] > 0, f1 = cnt[base + 1] > 0,
      f2 = cnt[base + 2] > 0, f3 = cnt[base + 3] > 0;
  int s = f0 + f1 + f2 + f3;
  buf[t] = s;
  __syncthreads();
  for (int off = 1; off < 1024; off <<= 1) {
    int add = (t >= off) ? buf[t - off] : 0;
    __syncthreads();
    buf[t] += add;
    __syncthreads();
  }
  int pos = buf[t] - s;
  if (f0) { occ_m[pos] = base + 0; inv[base + 0] = pos; pos++; }
  if (f1) { occ_m[pos] = base + 1; inv[base + 1] = pos; pos++; }
  if (f2) { occ_m[pos] = base + 2; inv[base + 2] = pos; pos++; }
  if (f3) { occ_m[pos] = base + 3; inv[base + 3] = pos; pos++; }
  if (t == 1023) noccPtr[0] = buf[1023];
  __syncthreads();

  // ---- phase 2: selection buckets (512) ----
  int v = (t < SBLK) ? selcnt[t] : 0;
  buf[t] = v;
  __syncthreads();
  for (int off = 1; off < 1024; off <<= 1) {
    int add = (t >= off) ? buf[t - off] : 0;
    __syncthreads();
    buf[t] += add;
    __syncthreads();
  }
  if (t < SBLK) {
    seloff[t + 1] = buf[t];
    selpos[t] = buf[t] - v;
    if (t == 0) seloff[0] = 0;
  }
  __syncthreads();

  // ---- phase 3: window buckets (729) ----
  int v2 = (t < NW3) ? wincnt[t] : 0;
  buf[t] = v2;
  __syncthreads();
  for (int off = 1; off < 1024; off <<= 1) {
    int add = (t >= off) ? buf[t - off] : 0;
    __syncthreads();
    buf[t] += add;
    __syncthreads();
  }
  if (t < NW3) {
    winoff[t + 1] = buf[t];
    winpos[t] = buf[t] - v2;
    if (t == 0) winoff[0] = 0;
  }
}

// =========================================================================
// scatter tokens into buckets
// =========================================================================
__global__ __launch_bounds__(256) void scatter(
    const int* __restrict__ sbid, const int* __restrict__ wid,
    int* __restrict__ selpos, int* __restrict__ winpos,
    int* __restrict__ sellist, int* __restrict__ winlist) {
  int n = blockIdx.x * 256 + threadIdx.x;
  if (n >= NT) return;
  int p = atomicAdd(&selpos[sbid[n]], 1);
  sellist[p] = n;
  int p2 = atomicAdd(&winpos[wid[n]], 1);
  winlist[p2] = n;
}

// =========================================================================
// generic f32 GEMM: C[rows,512] = A[rows,512] @ B[512,512]
// =========================================================================
__global__ __launch_bounds__(256) void gemm512(
    const float* __restrict__ A, const float* __restrict__ B, float* __restrict__ C,
    const int* __restrict__ nrowsPtr, int nrowsConst) {
  int nrows = nrowsPtr ? *nrowsPtr : nrowsConst;
  int rb = blockIdx.x, cb = blockIdx.y;
  int row0 = rb * 64, col0 = cb * 64;
  if (row0 >= nrows) return;
  __shared__ float As[64][17];
  __shared__ float Bs[16][68];
  int t = threadIdx.x;
  int tx = t & 15, ty = t >> 4;
  float acc[4][4] = {};
  for (int k0 = 0; k0 < 512; k0 += 16) {
    {
      int idx = t * 4; int r = idx >> 4; int kk = idx & 15;
      int gr = row0 + r;
      float4 va = (gr < nrows) ? *(const float4*)(A + (size_t)gr * 512 + k0 + kk)
                               : make_float4(0.f, 0.f, 0.f, 0.f);
      As[r][kk] = va.x; As[r][kk + 1] = va.y; As[r][kk + 2] = va.z; As[r][kk + 3] = va.w;
    }
    {
      int idx = t * 4; int kk = idx >> 6; int cc = idx & 63;
      float4 vb = *(const float4*)(B + (size_t)(k0 + kk) * 512 + col0 + cc);
      Bs[kk][cc] = vb.x; Bs[kk][cc + 1] = vb.y; Bs[kk][cc + 2] = vb.z; Bs[kk][cc + 3] = vb.w;
    }
    __syncthreads();
#pragma unroll
    for (int kk = 0; kk < 16; ++kk) {
      float a0 = As[ty * 4 + 0][kk], a1 = As[ty * 4 + 1][kk],
            a2 = As[ty * 4 + 2][kk], a3 = As[ty * 4 + 3][kk];
      float b0 = Bs[kk][tx * 4 + 0], b1 = Bs[kk][tx * 4 + 1],
            b2 = Bs[kk][tx * 4 + 2], b3 = Bs[kk][tx * 4 + 3];
      acc[0][0] += a0 * b0; acc[0][1] += a0 * b1; acc[0][2] += a0 * b2; acc[0][3] += a0 * b3;
      acc[1][0] += a1 * b0; acc[1][1] += a1 * b1; acc[1][2] += a1 * b2; acc[1][3] += a1 * b3;
      acc[2][0] += a2 * b0; acc[2][1] += a2 * b1; acc[2][2] += a2 * b2; acc[2][3] += a2 * b3;
      acc[3][0] += a3 * b0; acc[3][1] += a3 * b1; acc[3][2] += a3 * b2; acc[3][3] += a3 * b3;
    }
    __syncthreads();
  }
#pragma unroll
  for (int i = 0; i < 4; ++i) {
    int r = row0 + ty * 4 + i;
    if (r < nrows) {
#pragma unroll
      for (int j = 0; j < 4; ++j)
        C[(size_t)r * 512 + col0 + tx * 4 + j] = acc[i][j];
    }
  }
}

// =========================================================================
// gate: sigmoid(feats @ Wg)   Wg:[512,3]
// =========================================================================
__global__ __launch_bounds__(256) void gatek(
    const float* __restrict__ feats, const float* __restrict__ Wg,
    float* __restrict__ gates) {
  int idx = blockIdx.x * 256 + threadIdx.x;
  if (idx >= NT * 3) return;
  int n = idx / 3, g = idx % 3;
  const float* fp = feats + (size_t)n * 512;
  float s = 0.f;
  for (int i = 0; i < 512; ++i) s += fp[i] * Wg[i * 3 + g];
  gates[idx] = 1.f / (1.f + __expf(-s));
}

// =========================================================================
// segment accumulation into compacted block means (pre-division)
// =========================================================================
__global__ __launch_bounds__(256) void accum(
    const float* __restrict__ kf, const float* __restrict__ vf,
    const float* __restrict__ pe, const int* __restrict__ bid,
    const int* __restrict__ ibid, const int* __restrict__ inv,
    float* __restrict__ ksum, float* __restrict__ vsum) {
  int n = blockIdx.x;
  int t = threadIdx.x;
  int i = inv[bid[n]];
  const float* kp = kf + (size_t)n * 512;
  const float* vp = vf + (size_t)n * 512;
  const float* pp = pe + (size_t)ibid[n] * 512;
  float* kd = ksum + (size_t)i * 512;
  float* vd = vsum + (size_t)i * 512;
  atomicAdd(&kd[t], kp[t] + pp[t]);
  atomicAdd(&kd[t + 256], kp[t + 256] + pp[t + 256]);
  atomicAdd(&vd[t], vp[t]);
  atomicAdd(&vd[t + 256], vp[t + 256]);
}

__global__ __launch_bounds__(256) void divide_means(
    float* __restrict__ ksum, float* __restrict__ vsum,
    const int* __restrict__ occ_m, const int* __restrict__ cnt,
    const int* __restrict__ noccPtr, int* __restrict__ sid_key) {
  int idx = blockIdx.x * 256 + threadIdx.x;
  int i = idx >> 9;
  if (i >= *noccPtr) return;
  float rinv = 1.f / (float)cnt[occ_m[i]];
  ksum[idx] *= rinv;
  vsum[idx] *= rinv;
  if ((idx & 511) == 0) {
    int mm2 = occ_m[i];
    sid_key[i] = (((mm2 >> 9) & 7) << 6) | (((mm2 >> 5) & 7) << 3) | ((mm2 >> 1) & 7);
  }
}

// =========================================================================
// transpose compressed keys into ckT4: [dgroup=d/4][key (KPAD stride)][4]
// =========================================================================
__global__ __launch_bounds__(256) void transp(
    const float* __restrict__ src, float* __restrict__ dst,
    const int* __restrict__ noccPtr) {
  __shared__ float tile[64][65];
  int nocc = *noccPtr;
  int k0 = blockIdx.x * 64;   // key tile
  int d0 = blockIdx.y * 64;   // dim tile
  int c = threadIdx.x & 63, r0 = (threadIdx.x >> 6) * 16;
  for (int r = 0; r < 16; ++r) {
    int key = k0 + r0 + r;
    tile[r0 + r][c] = (key < nocc) ? src[(size_t)key * 512 + d0 + c] : 0.f;
  }
  __syncthreads();
  // lane c = key; write 4 dim-groups of this 64-dim tile
  float4* dst4 = (float4*)dst;
  int gl0 = (threadIdx.x >> 6) * 4;
#pragma unroll
  for (int gg = 0; gg < 4; ++gg) {
    int gl = gl0 + gg;                   // local dim-group 0..15
    float4 v = make_float4(tile[c][gl * 4 + 0], tile[c][gl * 4 + 1],
                           tile[c][gl * 4 + 2], tile[c][gl * 4 + 3]);
    dst4[(size_t)(d0 / 4 + gl) * KPAD + k0 + c] = v;
  }
}

// =========================================================================
// cattn stage 1 (clse): partial sum(exp(sc)) per (token, head) over a key
// half. grid (256 tok-groups, 2 key-halves), 1024 thr = 16 waves
// (8 heads x 2 key-subranges), 2-key register blocking, q in LDS.
// =========================================================================
__global__ __launch_bounds__(1024) void clse(
    const float* __restrict__ q, const float* __restrict__ ckT4,
    const int* __restrict__ noccPtr, float* __restrict__ lpart) {
  __shared__ float qlds[8 * 512];
  __shared__ float lred[16][8];
  const int n0 = blockIdx.x * 8;
  const int half = blockIdx.y;
  const int t = threadIdx.x;
  const int nocc = *noccPtr;
  const int kmid = (nocc + 1) >> 1;
  const int kbeg = half ? kmid : 0;
  const int kend = half ? nocc : kmid;
  const int w = t >> 6, l = t & 63;
  const int h = w & 7, sub = w >> 3;

  for (int idx = t; idx < 4096; idx += 1024)
    qlds[idx] = q[(size_t)n0 * 512 + idx];
  __syncthreads();

  const float4* ckp = (const float4*)ckT4 + (size_t)(h * 16) * KPAD;
  const float* qh = qlds + h * 64;

  float lacc[8];
#pragma unroll
  for (int tok = 0; tok < 8; ++tok) lacc[tok] = 0.f;

  for (int i0 = kbeg; i0 < kend; i0 += 256) {
    int iaRaw = i0 + sub * 128 + l;
    int ibRaw = iaRaw + 64;
    bool da = iaRaw < kend, db = ibRaw < kend;
    if (!da) continue;
    int ia = iaRaw;
    int ib = db ? ibRaw : iaRaw;
    float sa[8], sb[8];
#pragma unroll
    for (int tok = 0; tok < 8; ++tok) { sa[tok] = 0.f; sb[tok] = 0.f; }
#pragma unroll
    for (int c = 0; c < 16; ++c) {
      float4 ka = ckp[(size_t)c * KPAD + ia];
      float4 kb = ckp[(size_t)c * KPAD + ib];
#pragma unroll
      for (int tok = 0; tok < 8; ++tok) {
        float4 qv = *(const float4*)(qh + tok * 512 + c * 4);
        sa[tok] += ka.x * qv.x + ka.y * qv.y + ka.z * qv.z + ka.w * qv.w;
        sb[tok] += kb.x * qv.x + kb.y * qv.y + kb.z * qv.z + kb.w * qv.w;
      }
    }
#pragma unroll
    for (int tok = 0; tok < 8; ++tok) {
      lacc[tok] += __expf(sa[tok] * 0.125f);
      if (db) lacc[tok] += __expf(sb[tok] * 0.125f);
    }
  }

#pragma unroll
  for (int tok = 0; tok < 8; ++tok) {
    float l2 = lacc[tok];
#pragma unroll
    for (int s2 = 32; s2; s2 >>= 1) l2 += __shfl_xor(l2, s2, 64);
    if (l == 0) lred[w][tok] = l2;
  }
  __syncthreads();
  if (sub == 0 && l < 8) {
    // tok = l
    lpart[((size_t)half * NT + n0 + l) * 8 + h] = lred[h][l] + lred[8 + h][l];
  }
}

// =========================================================================
// cattn stage 2 (cpv): p = exp(sc)/l, PV partial accumulation, head-pooled
// selection-score accumulation. grid (256, 2 key-halves), 1024 thr =
// 8 heads x 2 key-sub-halves of a 128-key tile.
// =========================================================================
__global__ __launch_bounds__(1024) void cpv(
    const float* __restrict__ q, const float* __restrict__ ckT4,
    const float* __restrict__ cv, const int* __restrict__ sid_key,
    const int* __restrict__ noccPtr, const float* __restrict__ lpart,
    float* __restrict__ selsc_g, float* __restrict__ opart) {
  __shared__ float qlds[8 * 512];      // 16 KB
  __shared__ float pmat[8][8][128];    // 32 KB (reused as opart combine buf)
  __shared__ float selsc[8 * 512];     // 16 KB
  const int n0 = blockIdx.x * 8;
  const int half = blockIdx.y;
  const int t = threadIdx.x;
  const int nocc = *noccPtr;
  const int kmid = (nocc + 1) >> 1;
  const int kbeg = half ? kmid : 0;
  const int kend = half ? nocc : kmid;
  const int w = t >> 6, l = t & 63;
  const int h = w & 7, sub = w >> 3;

  for (int idx = t; idx < 4096; idx += 1024) {
    qlds[idx] = q[(size_t)n0 * 512 + idx];
    selsc[idx] = 0.f;
  }
  __syncthreads();

  float rl[8];
#pragma unroll
  for (int tok = 0; tok < 8; ++tok)
    rl[tok] = 1.f / (lpart[(size_t)(n0 + tok) * 8 + h] +
                     lpart[((size_t)NT + n0 + tok) * 8 + h]);

  const float4* ckp = (const float4*)ckT4 + (size_t)(h * 16) * KPAD;
  const float* qh = qlds + h * 64;

  float o[8];
#pragma unroll
  for (int tok = 0; tok < 8; ++tok) o[tok] = 0.f;

  for (int i0 = kbeg; i0 < kend; i0 += 128) {
    int lim = kend - i0; lim = lim > 128 ? 128 : lim;
    int iRaw = i0 + sub * 64 + l;
    bool valid = iRaw < kend;
    int ic = valid ? iRaw : (kend - 1);
    float s[8];
#pragma unroll
    for (int tok = 0; tok < 8; ++tok) s[tok] = 0.f;
#pragma unroll
    for (int c = 0; c < 16; ++c) {
      float4 kv = ckp[(size_t)c * KPAD + ic];
#pragma unroll
      for (int tok = 0; tok < 8; ++tok) {
        float4 qv = *(const float4*)(qh + tok * 512 + c * 4);
        s[tok] += kv.x * qv.x + kv.y * qv.y + kv.z * qv.z + kv.w * qv.w;
      }
    }
    float p[8];
#pragma unroll
    for (int tok = 0; tok < 8; ++tok)
      p[tok] = valid ? __expf(s[tok] * 0.125f) * rl[tok] : 0.f;
    __syncthreads();   // prior tile's pmat fully consumed
#pragma unroll
    for (int tok = 0; tok < 8; ++tok) pmat[h][tok][sub * 64 + l] = p[tok];
    __syncthreads();
    // head-pooled selection-score accumulation: thread = (j=t&127, tok=t>>7)
    {
      int j = t & 127, tk = t >> 7;
      if (j < lim) {
        float ps = 0.f;
#pragma unroll
        for (int hh = 0; hh < 8; ++hh) ps += pmat[hh][tk][j];
        atomicAdd(&selsc[tk * 512 + sid_key[i0 + j]], ps);
      }
    }
    // PV: lane = output dim; this sub-wave covers its 64-key half
    {
      int cnt_half = lim - sub * 64;
      cnt_half = cnt_half < 0 ? 0 : (cnt_half > 64 ? 64 : cnt_half);
      const float* cvp = cv + (size_t)(i0 + sub * 64) * 512 + h * 64 + l;
      int g4 = cnt_half >> 2;
      for (int g = 0; g < g4; ++g) {
        float v0 = cvp[(size_t)(g * 4 + 0) * 512];
        float v1 = cvp[(size_t)(g * 4 + 1) * 512];
        float v2 = cvp[(size_t)(g * 4 + 2) * 512];
        float v3 = cvp[(size_t)(g * 4 + 3) * 512];
#pragma unroll
        for (int tok = 0; tok < 8; ++tok) {
          float4 pm = *(const float4*)(&pmat[h][tok][sub * 64 + g * 4]);
          o[tok] += pm.x * v0 + pm.y * v1 + pm.z * v2 + pm.w * v3;
        }
      }
      for (int j = g4 * 4; j < cnt_half; ++j) {
        float v = cvp[(size_t)j * 512];
#pragma unroll
        for (int tok = 0; tok < 8; ++tok) o[tok] += pmat[h][tok][sub * 64 + j] * v;
      }
    }
  }

  // combine the two sub-halves' partial o, write opart[half]
  __syncthreads();
  float* obuf = &pmat[0][0][0];
  if (sub == 1) {
#pragma unroll
    for (int tok = 0; tok < 8; ++tok) obuf[(h * 8 + tok) * 64 + l] = o[tok];
  }
  __syncthreads();
  if (sub == 0) {
#pragma unroll
    for (int tok = 0; tok < 8; ++tok)
      opart[((size_t)half * NT + n0 + tok) * 512 + h * 64 + l] =
          o[tok] + obuf[(h * 8 + tok) * 64 + l];
  }
  // flush selection scores (atomics into global; zeroed each launch)
  for (int idx = t; idx < 4096; idx += 1024)
    atomicAdd(&selsc_g[(size_t)(n0 + (idx >> 9)) * 512 + (idx & 511)], selsc[idx]);
}

// =========================================================================
// cattn stage 3 (cfin): fused = gate0 * (opart0+opart1); top-8 from selsc_g
// =========================================================================
__global__ __launch_bounds__(64) void cfin(
    const float* __restrict__ opart, const float* __restrict__ selsc_g,
    const float* __restrict__ gates, float* __restrict__ fused,
    int* __restrict__ topk_out) {
  int n = blockIdx.x, t = threadIdx.x;
  float g0 = gates[n * 3];
  const float4* o0 = (const float4*)(opart + (size_t)n * 512);
  const float4* o1 = (const float4*)(opart + (size_t)(NT + n) * 512);
  float4* fp = (float4*)(fused + (size_t)n * 512);
#pragma unroll
  for (int r = 0; r < 2; ++r) {
    float4 a = o0[t + 64 * r], b = o1[t + 64 * r];
    fp[t + 64 * r] = make_float4(g0 * (a.x + b.x), g0 * (a.y + b.y),
                                 g0 * (a.z + b.z), g0 * (a.w + b.w));
  }
  const float* sp = selsc_g + (size_t)n * 512;
  float v[8];
#pragma unroll
  for (int r = 0; r < 8; ++r) v[r] = sp[r * 64 + t];
#pragma unroll
  for (int k = 0; k < 8; ++k) {
    float bv = v[0]; int bi = t;
#pragma unroll
    for (int r = 1; r < 8; ++r)
      if (v[r] > bv) { bv = v[r]; bi = r * 64 + t; }
#pragma unroll
    for (int s2 = 32; s2; s2 >>= 1) {
      float ov = __shfl_xor(bv, s2, 64);
      int oi = __shfl_xor(bi, s2, 64);
      if (ov > bv || (ov == bv && oi < bi)) { bv = ov; bi = oi; }
    }
    if (t == 0) topk_out[n * 8 + k] = bi;
#pragma unroll
    for (int r = 0; r < 8; ++r)
      if (bi == r * 64 + t) v[r] = NEGI;
  }
}

// =========================================================================
// selection + window attention (sparse, bucketed), adds into fused
// =========================================================================
__global__ __launch_bounds__(64) void selwin(
    const float* __restrict__ q, const float* __restrict__ kf,
    const float* __restrict__ vf, const int* __restrict__ topk,
    const int* __restrict__ seloff, const int* __restrict__ sellist,
    const int* __restrict__ winoff, const int* __restrict__ winlist,
    const int* __restrict__ wid_tok, const float* __restrict__ gates,
    float* __restrict__ fused) {
  int n = blockIdx.x, t = threadIdx.x;
  int h = t >> 3, j = t & 7;
  float q8[8];
  const float* qp = q + (size_t)n * 512 + h * 64 + j * 8;
#pragma unroll
  for (int d = 0; d < 8; ++d) q8[d] = qp[d];

  // ---- selection branch ----
  float os[8];
#pragma unroll
  for (int d = 0; d < 8; ++d) os[d] = 0.f;
  float m = NEGI, lsum = 0.f;
  for (int k = 0; k < 8; ++k) {
    int s = topk[n * 8 + k];
    int e0 = seloff[s], e1 = seloff[s + 1];
    for (int idx = e0; idx < e1; ++idx) {
      int tj = sellist[idx];
      const float* kp = kf + (size_t)tj * 512 + h * 64 + j * 8;
      float part = 0.f;
#pragma unroll
      for (int d = 0; d < 8; ++d) part += q8[d] * kp[d];
      part += __shfl_xor(part, 1, 64);
      part += __shfl_xor(part, 2, 64);
      part += __shfl_xor(part, 4, 64);
      float sc = part * 0.125f;
      float nm = fmaxf(m, sc);
      float scale = __expf(m - nm);
      float pv = __expf(sc - nm);
      const float* vp = vf + (size_t)tj * 512 + h * 64 + j * 8;
      lsum = lsum * scale + pv;
#pragma unroll
      for (int d = 0; d < 8; ++d) os[d] = os[d] * scale + pv * vp[d];
      m = nm;
    }
  }
  {
    float rl = (lsum > 0.f) ? 1.f / lsum : 0.f;
#pragma unroll
    for (int d = 0; d < 8; ++d) os[d] *= rl;
  }

  // ---- window branch ----
  float ow[8];
#pragma unroll
  for (int d = 0; d < 8; ++d) ow[d] = 0.f;
  m = NEGI; lsum = 0.f;
  int w = wid_tok[n];
  int e0 = winoff[w], e1 = winoff[w + 1];
  for (int idx = e0; idx < e1; ++idx) {
    int tj = winlist[idx];
    const float* kp = kf + (size_t)tj * 512 + h * 64 + j * 8;
    float part = 0.f;
#pragma unroll
    for (int d = 0; d < 8; ++d) part += q8[d] * kp[d];
    part += __shfl_xor(part, 1, 64);
    part += __shfl_xor(part, 2, 64);
    part += __shfl_xor(part, 4, 64);
    float sc = part * 0.125f;
    float nm = fmaxf(m, sc);
    float scale = __expf(m - nm);
    float pv = __expf(sc - nm);
    const float* vp = vf + (size_t)tj * 512 + h * 64 + j * 8;
    lsum = lsum * scale + pv;
#pragma unroll
    for (int d = 0; d < 8; ++d) ow[d] = ow[d] * scale + pv * vp[d];
    m = nm;
  }
  {
    float rl = (lsum > 0.f) ? 1.f / lsum : 0.f;
#pragma unroll
    for (int d = 0; d < 8; ++d) ow[d] *= rl;
  }

  float g1 = gates[n * 3 + 1], g2 = gates[n * 3 + 2];
  float* fp = fused + (size_t)n * 512 + h * 64 + j * 8;
#pragma unroll
  for (int d = 0; d < 8; ++d) fp[d] += g1 * os[d] + g2 * ow[d];
}

// =========================================================================
// launcher
// =========================================================================
extern "C" void kernel_launch(void* const* d_in, const int* in_sizes, int n_in,
                              void* d_out, int out_size, void* d_ws, size_t ws_size,
                              hipStream_t stream) {
  const float* feats = (const float*)d_in[0];
  const int* coords  = (const int*)d_in[1];
  const float* Wq  = (const float*)d_in[2];
  const float* Wk  = (const float*)d_in[3];
  const float* Wv  = (const float*)d_in[4];
  const float* Wo  = (const float*)d_in[5];
  const float* Wck = (const float*)d_in[6];
  const float* Wcv = (const float*)d_in[7];
  const float* pe  = (const float*)d_in[8];
  const float* Wg  = (const float*)d_in[9];
  float* out = (float*)d_out;

  char* p = (char*)d_ws;
  auto alloc = [&](size_t bytes) -> char* {
    char* r = p;
    p += (bytes + 255) & ~(size_t)255;
    return r;
  };
  float* q     = (float*)alloc((size_t)NT * 512 * 4);
  float* kf    = (float*)alloc((size_t)NT * 512 * 4);
  float* vf    = (float*)alloc((size_t)NT * 512 * 4);
  float* fused = (float*)alloc((size_t)NT * 512 * 4);
  float* zf    = (float*)alloc((size_t)2 * NT * 512 * 4);  // ckbar|cvbar (zeroed)
  float* ckbar = zf;
  float* cvbar = zf + (size_t)NT * 512;
  float* ckc   = (float*)alloc((size_t)NT * 512 * 4);
  float* cvc   = (float*)alloc((size_t)NT * 512 * 4);
  float* ckT   = (float*)alloc((size_t)512 * KPAD * 4);
  float* gates = (float*)alloc((size_t)NT * 3 * 4);
  float* lpart = (float*)alloc((size_t)2 * NT * 8 * 4);
  float* selsc_g = (float*)alloc((size_t)NT * SBLK * 4);   // zeroed each launch
  float* opart = (float*)alloc((size_t)2 * NT * 512 * 4);
  int* zi      = (int*)alloc((size_t)(MBLK + SBLK + NW3) * 4);  // cnt|selcnt|wincnt
  int* cnt = zi;
  int* selcnt = zi + MBLK;
  int* wincnt = zi + MBLK + SBLK;
  int* inv     = (int*)alloc((size_t)MBLK * 4);
  int* occ     = (int*)alloc((size_t)NT * 4);
  int* nocc    = (int*)alloc(4);
  int* bid     = (int*)alloc((size_t)NT * 4);
  int* sbid    = (int*)alloc((size_t)NT * 4);
  int* wid     = (int*)alloc((size_t)NT * 4);
  int* ibid    = (int*)alloc((size_t)NT * 4);
  int* sid_key = (int*)alloc((size_t)NT * 4);
  int* seloff  = (int*)alloc((size_t)(SBLK + 1) * 4);
  int* selpos  = (int*)alloc((size_t)SBLK * 4);
  int* sellist = (int*)alloc((size_t)NT * 4);
  int* winoff  = (int*)alloc((size_t)(NW3 + 1) * 4);
  int* winpos  = (int*)alloc((size_t)NW3 * 4);
  int* winlist = (int*)alloc((size_t)NT * 4);
  int* topk    = (int*)alloc((size_t)NT * 8 * 4);

  hipMemsetAsync(zf, 0, (size_t)2 * NT * 512 * 4, stream);
  hipMemsetAsync(zi, 0, (size_t)(MBLK + SBLK + NW3) * 4, stream);
  hipMemsetAsync(selsc_g, 0, (size_t)NT * SBLK * 4, stream);

  token_prep<<<8, 256, 0, stream>>>(coords, bid, sbid, wid, ibid, cnt, selcnt, wincnt);
  scan_all<<<1, 1024, 0, stream>>>(cnt, occ, inv, nocc, selcnt, seloff, selpos,
                                   wincnt, winoff, winpos);
  scatter<<<8, 256, 0, stream>>>(sbid, wid, selpos, winpos, sellist, winlist);

  dim3 gg(32, 8);
  gemm512<<<gg, 256, 0, stream>>>(feats, Wq, q, nullptr, NT);
  gemm512<<<gg, 256, 0, stream>>>(feats, Wk, kf, nullptr, NT);
  gemm512<<<gg, 256, 0, stream>>>(feats, Wv, vf, nullptr, NT);
  gatek<<<24, 256, 0, stream>>>(feats, Wg, gates);

  accum<<<NT, 256, 0, stream>>>(kf, vf, pe, bid, ibid, inv, ckbar, cvbar);
  divide_means<<<4096, 256, 0, stream>>>(ckbar, cvbar, occ, cnt, nocc, sid_key);
  gemm512<<<gg, 256, 0, stream>>>(ckbar, Wck, ckc, nocc, 0);
  gemm512<<<gg, 256, 0, stream>>>(cvbar, Wcv, cvc, nocc, 0);
  transp<<<dim3(32, 8), 256, 0, stream>>>(ckc, ckT, nocc);

  clse<<<dim3(256, 2), 1024, 0, stream>>>(q, ckT, nocc, lpart);
  cpv<<<dim3(256, 2), 1024, 0, stream>>>(q, ckT, cvc, sid_key, nocc, lpart,
                                         selsc_g, opart);
  cfin<<<NT, 64, 0, stream>>>(opart, selsc_g, gates, fused, topk);

  selwin<<<NT, 64, 0, stream>>>(q, kf, vf, topk, seloff, sellist, winoff, winlist,
                                wid, gates, fused);
  gemm512<<<gg, 256, 0, stream>>>(fused, Wo, out, nullptr, NT);
}

// Round 5
// 605.467 us; speedup vs baseline: 9.4669x; 9.4669x over previous
//
#include <hip/hip_runtime.h>

// ---- problem constants ----
constexpr int NT   = 2048;   // tokens
constexpr int HD   = 512;    // hidden = HQ*D = HKV*D
constexpr int MBLK = 4096;   // 16^3 compression block slots
constexpr int SBLK = 512;    // 8^3 selection block slots
constexpr int NW3  = 729;    // 9^3 shifted windows
constexpr int KPAD = 2048;   // padded key stride for ckT
#define NEGI (-1e30f)

// =========================================================================
// token prep: coords decode, ids, bucket counts
// =========================================================================
__global__ __launch_bounds__(256) void token_prep(
    const int* __restrict__ cf, int* __restrict__ bid, int* __restrict__ sbid,
    int* __restrict__ wid, int* __restrict__ ibid, int* __restrict__ cnt,
    int* __restrict__ selcnt, int* __restrict__ wincnt) {
  int n = blockIdx.x * 256 + threadIdx.x;
  if (n >= NT) return;
  int c = cf[n];
  int x = c >> 12, y = (c >> 6) & 63, z = c & 63;
  int b  = ((x >> 2) << 8) | ((y >> 2) << 4) | (z >> 2);
  int sb = ((x >> 3) << 6) | ((y >> 3) << 3) | (z >> 3);
  int w  = ((x + 4) >> 3) * 81 + ((y + 4) >> 3) * 9 + ((z + 4) >> 3);
  int ib = ((x & 3) << 4) | ((y & 3) << 2) | (z & 3);
  bid[n] = b; sbid[n] = sb; wid[n] = w; ibid[n] = ib;
  atomicAdd(&cnt[b], 1);
  atomicAdd(&selcnt[sb], 1);
  atomicAdd(&wincnt[w], 1);
}

// =========================================================================
// single-block scans: occupied-block compaction + bucket offsets
// =========================================================================
__global__ __launch_bounds__(1024) void scan_all(
    const int* __restrict__ cnt, int* __restrict__ occ_m, int* __restrict__ inv,
    int* __restrict__ noccPtr,
    const int* __restrict__ selcnt, int* __restrict__ seloff, int* __restrict__ selpos,
    const int* __restrict__ wincnt, int* __restrict__ winoff, int* __restrict__ winpos) {
  __shared__ int buf[1024];
  int t = threadIdx.x;

  // ---- phase 1: compaction scan over MBLK=4096 (4 per thread) ----
  int base = t * 4;
  int f0 = cnt[base + 0] > 0, f1 = cnt[base + 1] > 0,
      f2 = cnt[base + 2] > 0, f3 = cnt[base + 3] > 0;
  int s = f0 + f1 + f2 + f3;
  buf[t] = s;
  __syncthreads();
  for (int off = 1; off < 1024; off <<= 1) {
    int add = (t >= off) ? buf[t - off] : 0;
    __syncthreads();
    buf[t] += add;
    __syncthreads();
  }
  int pos = buf[t] - s;
  if (f0) { occ_m[pos] = base + 0; inv[base + 0] = pos; pos++; }
  if (f1) { occ_m[pos] = base + 1; inv[base + 1] = pos; pos++; }
  if (f2) { occ_m[pos] = base + 2; inv[base + 2] = pos; pos++; }
  if (f3) { occ_m[pos] = base + 3; inv[base + 3] = pos; pos++; }
  if (t == 1023) noccPtr[0] = buf[1023];
  __syncthreads();

  // ---- phase 2: selection buckets (512) ----
  int v = (t < SBLK) ? selcnt[t] : 0;
  buf[t] = v;
  __syncthreads();
  for (int off = 1; off < 1024; off <<= 1) {
    int add = (t >= off) ? buf[t - off] : 0;
    __syncthreads();
    buf[t] += add;
    __syncthreads();
  }
  if (t < SBLK) {
    seloff[t + 1] = buf[t];
    selpos[t] = buf[t] - v;
    if (t == 0) seloff[0] = 0;
  }
  __syncthreads();

  // ---- phase 3: window buckets (729) ----
  int v2 = (t < NW3) ? wincnt[t] : 0;
  buf[t] = v2;
  __syncthreads();
  for (int off = 1; off < 1024; off <<= 1) {
    int add = (t >= off) ? buf[t - off] : 0;
    __syncthreads();
    buf[t] += add;
    __syncthreads();
  }
  if (t < NW3) {
    winoff[t + 1] = buf[t];
    winpos[t] = buf[t] - v2;
    if (t == 0) winoff[0] = 0;
  }
}

// =========================================================================
// scatter tokens into buckets
// =========================================================================
__global__ __launch_bounds__(256) void scatter(
    const int* __restrict__ sbid, const int* __restrict__ wid,
    int* __restrict__ selpos, int* __restrict__ winpos,
    int* __restrict__ sellist, int* __restrict__ winlist) {
  int n = blockIdx.x * 256 + threadIdx.x;
  if (n >= NT) return;
  int p = atomicAdd(&selpos[sbid[n]], 1);
  sellist[p] = n;
  int p2 = atomicAdd(&winpos[wid[n]], 1);
  winlist[p2] = n;
}

// =========================================================================
// generic f32 GEMM: C[rows,512] = A[rows,512] @ B[512,512]
// =========================================================================
__global__ __launch_bounds__(256) void gemm512(
    const float* __restrict__ A, const float* __restrict__ B, float* __restrict__ C,
    const int* __restrict__ nrowsPtr, int nrowsConst) {
  int nrows = nrowsPtr ? *nrowsPtr : nrowsConst;
  int rb = blockIdx.x, cb = blockIdx.y;
  int row0 = rb * 64, col0 = cb * 64;
  if (row0 >= nrows) return;
  __shared__ float As[64][17];
  __shared__ float Bs[16][68];
  int t = threadIdx.x;
  int tx = t & 15, ty = t >> 4;
  float acc[4][4] = {};
  for (int k0 = 0; k0 < 512; k0 += 16) {
    {
      int idx = t * 4; int r = idx >> 4; int kk = idx & 15;
      int gr = row0 + r;
      float4 va = (gr < nrows) ? *(const float4*)(A + (size_t)gr * 512 + k0 + kk)
                               : make_float4(0.f, 0.f, 0.f, 0.f);
      As[r][kk] = va.x; As[r][kk + 1] = va.y; As[r][kk + 2] = va.z; As[r][kk + 3] = va.w;
    }
    {
      int idx = t * 4; int kk = idx >> 6; int cc = idx & 63;
      float4 vb = *(const float4*)(B + (size_t)(k0 + kk) * 512 + col0 + cc);
      Bs[kk][cc] = vb.x; Bs[kk][cc + 1] = vb.y; Bs[kk][cc + 2] = vb.z; Bs[kk][cc + 3] = vb.w;
    }
    __syncthreads();
#pragma unroll
    for (int kk = 0; kk < 16; ++kk) {
      float a0 = As[ty * 4 + 0][kk], a1 = As[ty * 4 + 1][kk],
            a2 = As[ty * 4 + 2][kk], a3 = As[ty * 4 + 3][kk];
      float b0 = Bs[kk][tx * 4 + 0], b1 = Bs[kk][tx * 4 + 1],
            b2 = Bs[kk][tx * 4 + 2], b3 = Bs[kk][tx * 4 + 3];
      acc[0][0] += a0 * b0; acc[0][1] += a0 * b1; acc[0][2] += a0 * b2; acc[0][3] += a0 * b3;
      acc[1][0] += a1 * b0; acc[1][1] += a1 * b1; acc[1][2] += a1 * b2; acc[1][3] += a1 * b3;
      acc[2][0] += a2 * b0; acc[2][1] += a2 * b1; acc[2][2] += a2 * b2; acc[2][3] += a2 * b3;
      acc[3][0] += a3 * b0; acc[3][1] += a3 * b1; acc[3][2] += a3 * b2; acc[3][3] += a3 * b3;
    }
    __syncthreads();
  }
#pragma unroll
  for (int i = 0; i < 4; ++i) {
    int r = row0 + ty * 4 + i;
    if (r < nrows) {
#pragma unroll
      for (int j = 0; j < 4; ++j)
        C[(size_t)r * 512 + col0 + tx * 4 + j] = acc[i][j];
    }
  }
}

// =========================================================================
// gate: sigmoid(feats @ Wg)   Wg:[512,3]
// =========================================================================
__global__ __launch_bounds__(256) void gatek(
    const float* __restrict__ feats, const float* __restrict__ Wg,
    float* __restrict__ gates) {
  int idx = blockIdx.x * 256 + threadIdx.x;
  if (idx >= NT * 3) return;
  int n = idx / 3, g = idx % 3;
  const float* fp = feats + (size_t)n * 512;
  float s = 0.f;
  for (int i = 0; i < 512; ++i) s += fp[i] * Wg[i * 3 + g];
  gates[idx] = 1.f / (1.f + __expf(-s));
}

// =========================================================================
// segment accumulation into compacted block means (pre-division)
// =========================================================================
__global__ __launch_bounds__(256) void accum(
    const float* __restrict__ kf, const float* __restrict__ vf,
    const float* __restrict__ pe, const int* __restrict__ bid,
    const int* __restrict__ ibid, const int* __restrict__ inv,
    float* __restrict__ ksum, float* __restrict__ vsum) {
  int n = blockIdx.x;
  int t = threadIdx.x;
  int i = inv[bid[n]];
  const float* kp = kf + (size_t)n * 512;
  const float* vp = vf + (size_t)n * 512;
  const float* pp = pe + (size_t)ibid[n] * 512;
  float* kd = ksum + (size_t)i * 512;
  float* vd = vsum + (size_t)i * 512;
  atomicAdd(&kd[t], kp[t] + pp[t]);
  atomicAdd(&kd[t + 256], kp[t + 256] + pp[t + 256]);
  atomicAdd(&vd[t], vp[t]);
  atomicAdd(&vd[t + 256], vp[t + 256]);
}

__global__ __launch_bounds__(256) void divide_means(
    float* __restrict__ ksum, float* __restrict__ vsum,
    const int* __restrict__ occ_m, const int* __restrict__ cnt,
    const int* __restrict__ noccPtr, int* __restrict__ sid_key) {
  int idx = blockIdx.x * 256 + threadIdx.x;
  int i = idx >> 9;
  if (i >= *noccPtr) return;
  float rinv = 1.f / (float)cnt[occ_m[i]];
  ksum[idx] *= rinv;
  vsum[idx] *= rinv;
  if ((idx & 511) == 0) {
    int mm2 = occ_m[i];
    sid_key[i] = (((mm2 >> 9) & 7) << 6) | (((mm2 >> 5) & 7) << 3) | ((mm2 >> 1) & 7);
  }
}

// =========================================================================
// transpose compressed keys: ckT[d][key] (KPAD stride) from ckc[key][d]
// =========================================================================
__global__ __launch_bounds__(256) void transp(
    const float* __restrict__ src, float* __restrict__ dst,
    const int* __restrict__ noccPtr) {
  __shared__ float tile[64][65];
  int nocc = *noccPtr;
  int k0 = blockIdx.x * 64;   // key tile
  int d0 = blockIdx.y * 64;   // dim tile
  int c = threadIdx.x & 63, r0 = (threadIdx.x >> 6) * 16;
  for (int r = 0; r < 16; ++r) {
    int key = k0 + r0 + r;
    tile[r0 + r][c] = (key < nocc) ? src[(size_t)key * 512 + d0 + c] : 0.f;
  }
  __syncthreads();
  for (int r = 0; r < 16; ++r)
    dst[(size_t)(d0 + r0 + r) * KPAD + k0 + c] = tile[c][r0 + r];
}

// =========================================================================
// cattn stage 1 (clse): partial sum(exp(sc)) per (token, head) over a key
// half (blockIdx.y). 1024 thr = 16 waves = 8 heads x 2 key-subranges.
// R3 pass-A body verbatim (low VGPR: lacc[8]+sacc[8], scalar ckT dwords,
// wave-uniform q scalar loads).
// =========================================================================
__global__ __launch_bounds__(1024) void clse(
    const float* __restrict__ q, const float* __restrict__ ckT,
    const int* __restrict__ noccPtr, float* __restrict__ lpart) {
  __shared__ float lred[16][8];
  const int n0 = blockIdx.x * 8;
  const int half = blockIdx.y;
  const int t = threadIdx.x;
  const int nocc = *noccPtr;
  const int kmid = (nocc + 1) >> 1;
  const int kbeg = half ? kmid : 0;
  const int kend = half ? nocc : kmid;
  const int w = t >> 6, l = t & 63;
  const int h   = __builtin_amdgcn_readfirstlane(w & 7);
  const int sub = __builtin_amdgcn_readfirstlane(w >> 3);

  const float* ckTh = ckT + (size_t)h * 64 * KPAD;
  const size_t qbase = (size_t)n0 * 512 + h * 64;

  float lacc[8];
#pragma unroll
  for (int tok = 0; tok < 8; ++tok) lacc[tok] = 0.f;

  for (int i0 = kbeg; i0 < kend; i0 += 128) {
    int i = i0 + sub * 64 + l;
    if (i < kend) {
      float sacc[8];
#pragma unroll
      for (int tok = 0; tok < 8; ++tok) sacc[tok] = 0.f;
      for (int c = 0; c < 8; ++c) {
#pragma unroll
        for (int dd = 0; dd < 8; ++dd) {
          float kv = ckTh[(size_t)(c * 8 + dd) * KPAD + i];
#pragma unroll
          for (int tok = 0; tok < 8; ++tok)
            sacc[tok] += kv * q[qbase + (size_t)tok * 512 + c * 8 + dd];
        }
      }
#pragma unroll
      for (int tok = 0; tok < 8; ++tok)
        lacc[tok] += __expf(sacc[tok] * 0.125f);
    }
  }
#pragma unroll
  for (int tok = 0; tok < 8; ++tok) {
    float l2 = lacc[tok];
#pragma unroll
    for (int s2 = 32; s2; s2 >>= 1) l2 += __shfl_xor(l2, s2, 64);
    if (l == 0) lred[w][tok] = l2;
  }
  __syncthreads();
  if (t < 64) {
    int h2 = t & 7, tok = t >> 3;
    lpart[((size_t)half * NT + n0 + tok) * 8 + h2] =
        lred[h2][tok] + lred[h2 + 8][tok];
  }
}

// =========================================================================
// cattn stage 2 (cpv): p = exp(sc)/l, partial PV, head-pooled selection
// scores (LDS atomics, flushed with plain stores to per-half buffer).
// R3 pass-B body verbatim; key range = half.
// =========================================================================
__global__ __launch_bounds__(1024) void cpv(
    const float* __restrict__ q, const float* __restrict__ ckT,
    const float* __restrict__ cv, const int* __restrict__ sid_key,
    const int* __restrict__ noccPtr, const float* __restrict__ lpart,
    float* __restrict__ selsc_h, float* __restrict__ opart) {
  __shared__ float selsc[8 * 512];      // 16 KB
  __shared__ float pmat[8][8][128];     // 32 KB (reused as o-combine buf)
  __shared__ int   sid_l[128];
  const int n0 = blockIdx.x * 8;
  const int half = blockIdx.y;
  const int t = threadIdx.x;
  const int nocc = *noccPtr;
  const int kmid = (nocc + 1) >> 1;
  const int kbeg = half ? kmid : 0;
  const int kend = half ? nocc : kmid;
  const int w = t >> 6, l = t & 63;
  const int h   = __builtin_amdgcn_readfirstlane(w & 7);
  const int sub = __builtin_amdgcn_readfirstlane(w >> 3);

  for (int idx = t; idx < 4096; idx += 1024) selsc[idx] = 0.f;
  __syncthreads();

  const float* ckTh = ckT + (size_t)h * 64 * KPAD;
  const size_t qbase = (size_t)n0 * 512 + h * 64;

  float rl[8];
#pragma unroll
  for (int tok = 0; tok < 8; ++tok)
    rl[tok] = 1.f / (lpart[(size_t)(n0 + tok) * 8 + h] +
                     lpart[((size_t)NT + n0 + tok) * 8 + h]);

  float o[8];
#pragma unroll
  for (int tok = 0; tok < 8; ++tok) o[tok] = 0.f;

  for (int i0 = kbeg; i0 < kend; i0 += 128) {
    int lim = kend - i0; lim = lim > 128 ? 128 : lim;
    int i = i0 + sub * 64 + l;
    bool valid = i < kend;
    float p[8];
    if (valid) {
      float sacc[8];
#pragma unroll
      for (int tok = 0; tok < 8; ++tok) sacc[tok] = 0.f;
      for (int c = 0; c < 8; ++c) {
#pragma unroll
        for (int dd = 0; dd < 8; ++dd) {
          float kv = ckTh[(size_t)(c * 8 + dd) * KPAD + i];
#pragma unroll
          for (int tok = 0; tok < 8; ++tok)
            sacc[tok] += kv * q[qbase + (size_t)tok * 512 + c * 8 + dd];
        }
      }
#pragma unroll
      for (int tok = 0; tok < 8; ++tok)
        p[tok] = __expf(sacc[tok] * 0.125f) * rl[tok];
    }
    __syncthreads();   // prior tile's pmat fully consumed
    if (valid) {
#pragma unroll
      for (int tok = 0; tok < 8; ++tok) pmat[h][tok][sub * 64 + l] = p[tok];
    }
    if (t < 128 && t < lim) sid_l[t] = sid_key[kbeg + (i0 - kbeg) + t];
    __syncthreads();
    // head-pooled selection-score accumulation: thread = (j=t&127, tok=t>>7)
    {
      int j = t & 127, tk = t >> 7;
      if (j < lim) {
        float ps = 0.f;
#pragma unroll
        for (int hh = 0; hh < 8; ++hh) ps += pmat[hh][tk][j];
        atomicAdd(&selsc[tk * 512 + sid_l[j]], ps);
      }
    }
    // PV: lane = output dim; this sub-wave covers its 64-key half
    {
      int cnt_half = lim - sub * 64;
      cnt_half = cnt_half < 0 ? 0 : (cnt_half > 64 ? 64 : cnt_half);
      const float* cvp = cv + (size_t)(i0 + sub * 64) * 512 + h * 64 + l;
      int g4 = cnt_half >> 2;
      for (int g = 0; g < g4; ++g) {
        float v0 = cvp[(size_t)(g * 4 + 0) * 512];
        float v1 = cvp[(size_t)(g * 4 + 1) * 512];
        float v2 = cvp[(size_t)(g * 4 + 2) * 512];
        float v3 = cvp[(size_t)(g * 4 + 3) * 512];
#pragma unroll
        for (int tok = 0; tok < 8; ++tok) {
          float4 pm = *(const float4*)(&pmat[h][tok][sub * 64 + g * 4]);
          o[tok] += pm.x * v0 + pm.y * v1 + pm.z * v2 + pm.w * v3;
        }
      }
      for (int j = g4 * 4; j < cnt_half; ++j) {
        float v = cvp[(size_t)j * 512];
#pragma unroll
        for (int tok = 0; tok < 8; ++tok) o[tok] += pmat[h][tok][sub * 64 + j] * v;
      }
    }
  }

  // combine the two sub-halves' partial o, write opart[half]
  __syncthreads();
  float* obuf = &pmat[0][0][0];
  if (sub == 1) {
#pragma unroll
    for (int tok = 0; tok < 8; ++tok) obuf[(h * 8 + tok) * 64 + l] = o[tok];
  }
  __syncthreads();
  if (sub == 0) {
#pragma unroll
    for (int tok = 0; tok < 8; ++tok)
      opart[((size_t)half * NT + n0 + tok) * 512 + h * 64 + l] =
          o[tok] + obuf[(h * 8 + tok) * 64 + l];
  }
  // flush selection scores: plain coalesced stores to per-half buffer
  for (int idx = t; idx < 4096; idx += 1024)
    selsc_h[((size_t)half * NT + n0 + (idx >> 9)) * 512 + (idx & 511)] = selsc[idx];
}

// =========================================================================
// cattn stage 3 (cfin): fused = gate0 * (opart0+opart1); top-8 from summed
// per-half selection scores.
// =========================================================================
__global__ __launch_bounds__(64) void cfin(
    const float* __restrict__ opart, const float* __restrict__ selsc_h,
    const float* __restrict__ gates, float* __restrict__ fused,
    int* __restrict__ topk_out) {
  int n = blockIdx.x, t = threadIdx.x;
  float g0 = gates[n * 3];
  const float4* o0 = (const float4*)(opart + (size_t)n * 512);
  const float4* o1 = (const float4*)(opart + (size_t)(NT + n) * 512);
  float4* fp = (float4*)(fused + (size_t)n * 512);
#pragma unroll
  for (int r = 0; r < 2; ++r) {
    float4 a = o0[t + 64 * r], b = o1[t + 64 * r];
    fp[t + 64 * r] = make_float4(g0 * (a.x + b.x), g0 * (a.y + b.y),
                                 g0 * (a.z + b.z), g0 * (a.w + b.w));
  }
  const float* sp0 = selsc_h + (size_t)n * 512;
  const float* sp1 = selsc_h + (size_t)(NT + n) * 512;
  float v[8];
#pragma unroll
  for (int r = 0; r < 8; ++r) v[r] = sp0[r * 64 + t] + sp1[r * 64 + t];
#pragma unroll
  for (int k = 0; k < 8; ++k) {
    float bv = v[0]; int bi = t;
#pragma unroll
    for (int r = 1; r < 8; ++r)
      if (v[r] > bv) { bv = v[r]; bi = r * 64 + t; }
#pragma unroll
    for (int s2 = 32; s2; s2 >>= 1) {
      float ov = __shfl_xor(bv, s2, 64);
      int oi = __shfl_xor(bi, s2, 64);
      if (ov > bv || (ov == bv && oi < bi)) { bv = ov; bi = oi; }
    }
    if (t == 0) topk_out[n * 8 + k] = bi;
#pragma unroll
    for (int r = 0; r < 8; ++r)
      if (bi == r * 64 + t) v[r] = NEGI;
  }
}

// =========================================================================
// selection + window attention (sparse, bucketed), adds into fused
// =========================================================================
__global__ __launch_bounds__(64) void selwin(
    const float* __restrict__ q, const float* __restrict__ kf,
    const float* __restrict__ vf, const int* __restrict__ topk,
    const int* __restrict__ seloff, const int* __restrict__ sellist,
    const int* __restrict__ winoff, const int* __restrict__ winlist,
    const int* __restrict__ wid_tok, const float* __restrict__ gates,
    float* __restrict__ fused) {
  int n = blockIdx.x, t = threadIdx.x;
  int h = t >> 3, j = t & 7;
  float q8[8];
  const float* qp = q + (size_t)n * 512 + h * 64 + j * 8;
#pragma unroll
  for (int d = 0; d < 8; ++d) q8[d] = qp[d];

  // ---- selection branch ----
  float os[8];
#pragma unroll
  for (int d = 0; d < 8; ++d) os[d] = 0.f;
  float m = NEGI, lsum = 0.f;
  for (int k = 0; k < 8; ++k) {
    int s = topk[n * 8 + k];
    int e0 = seloff[s], e1 = seloff[s + 1];
    for (int idx = e0; idx < e1; ++idx) {
      int tj = sellist[idx];
      const float* kp = kf + (size_t)tj * 512 + h * 64 + j * 8;
      float part = 0.f;
#pragma unroll
      for (int d = 0; d < 8; ++d) part += q8[d] * kp[d];
      part += __shfl_xor(part, 1, 64);
      part += __shfl_xor(part, 2, 64);
      part += __shfl_xor(part, 4, 64);
      float sc = part * 0.125f;
      float nm = fmaxf(m, sc);
      float scale = __expf(m - nm);
      float pv = __expf(sc - nm);
      const float* vp = vf + (size_t)tj * 512 + h * 64 + j * 8;
      lsum = lsum * scale + pv;
#pragma unroll
      for (int d = 0; d < 8; ++d) os[d] = os[d] * scale + pv * vp[d];
      m = nm;
    }
  }
  {
    float rl = (lsum > 0.f) ? 1.f / lsum : 0.f;
#pragma unroll
    for (int d = 0; d < 8; ++d) os[d] *= rl;
  }

  // ---- window branch ----
  float ow[8];
#pragma unroll
  for (int d = 0; d < 8; ++d) ow[d] = 0.f;
  m = NEGI; lsum = 0.f;
  int w = wid_tok[n];
  int e0 = winoff[w], e1 = winoff[w + 1];
  for (int idx = e0; idx < e1; ++idx) {
    int tj = winlist[idx];
    const float* kp = kf + (size_t)tj * 512 + h * 64 + j * 8;
    float part = 0.f;
#pragma unroll
    for (int d = 0; d < 8; ++d) part += q8[d] * kp[d];
    part += __shfl_xor(part, 1, 64);
    part += __shfl_xor(part, 2, 64);
    part += __shfl_xor(part, 4, 64);
    float sc = part * 0.125f;
    float nm = fmaxf(m, sc);
    float scale = __expf(m - nm);
    float pv = __expf(sc - nm);
    const float* vp = vf + (size_t)tj * 512 + h * 64 + j * 8;
    lsum = lsum * scale + pv;
#pragma unroll
    for (int d = 0; d < 8; ++d) ow[d] = ow[d] * scale + pv * vp[d];
    m = nm;
  }
  {
    float rl = (lsum > 0.f) ? 1.f / lsum : 0.f;
#pragma unroll
    for (int d = 0; d < 8; ++d) ow[d] *= rl;
  }

  float g1 = gates[n * 3 + 1], g2 = gates[n * 3 + 2];
  float* fp = fused + (size_t)n * 512 + h * 64 + j * 8;
#pragma unroll
  for (int d = 0; d < 8; ++d) fp[d] += g1 * os[d] + g2 * ow[d];
}

// =========================================================================
// launcher
// =========================================================================
extern "C" void kernel_launch(void* const* d_in, const int* in_sizes, int n_in,
                              void* d_out, int out_size, void* d_ws, size_t ws_size,
                              hipStream_t stream) {
  const float* feats = (const float*)d_in[0];
  const int* coords  = (const int*)d_in[1];
  const float* Wq  = (const float*)d_in[2];
  const float* Wk  = (const float*)d_in[3];
  const float* Wv  = (const float*)d_in[4];
  const float* Wo  = (const float*)d_in[5];
  const float* Wck = (const float*)d_in[6];
  const float* Wcv = (const float*)d_in[7];
  const float* pe  = (const float*)d_in[8];
  const float* Wg  = (const float*)d_in[9];
  float* out = (float*)d_out;

  char* p = (char*)d_ws;
  auto alloc = [&](size_t bytes) -> char* {
    char* r = p;
    p += (bytes + 255) & ~(size_t)255;
    return r;
  };
  float* q     = (float*)alloc((size_t)NT * 512 * 4);
  float* kf    = (float*)alloc((size_t)NT * 512 * 4);
  float* vf    = (float*)alloc((size_t)NT * 512 * 4);
  float* fused = (float*)alloc((size_t)NT * 512 * 4);
  float* zf    = (float*)alloc((size_t)2 * NT * 512 * 4);  // ckbar|cvbar (zeroed)
  float* ckbar = zf;
  float* cvbar = zf + (size_t)NT * 512;
  float* ckc   = (float*)alloc((size_t)NT * 512 * 4);
  float* cvc   = (float*)alloc((size_t)NT * 512 * 4);
  float* ckT   = (float*)alloc((size_t)512 * KPAD * 4);
  float* gates = (float*)alloc((size_t)NT * 3 * 4);
  float* lpart = (float*)alloc((size_t)2 * NT * 8 * 4);
  float* selsc_h = (float*)alloc((size_t)2 * NT * SBLK * 4);
  float* opart = (float*)alloc((size_t)2 * NT * 512 * 4);
  int* zi      = (int*)alloc((size_t)(MBLK + SBLK + NW3) * 4);  // cnt|selcnt|wincnt
  int* cnt = zi;
  int* selcnt = zi + MBLK;
  int* wincnt = zi + MBLK + SBLK;
  int* inv     = (int*)alloc((size_t)MBLK * 4);
  int* occ     = (int*)alloc((size_t)NT * 4);
  int* nocc    = (int*)alloc(4);
  int* bid     = (int*)alloc((size_t)NT * 4);
  int* sbid    = (int*)alloc((size_t)NT * 4);
  int* wid     = (int*)alloc((size_t)NT * 4);
  int* ibid    = (int*)alloc((size_t)NT * 4);
  int* sid_key = (int*)alloc((size_t)NT * 4);
  int* seloff  = (int*)alloc((size_t)(SBLK + 1) * 4);
  int* selpos  = (int*)alloc((size_t)SBLK * 4);
  int* sellist = (int*)alloc((size_t)NT * 4);
  int* winoff  = (int*)alloc((size_t)(NW3 + 1) * 4);
  int* winpos  = (int*)alloc((size_t)NW3 * 4);
  int* winlist = (int*)alloc((size_t)NT * 4);
  int* topk    = (int*)alloc((size_t)NT * 8 * 4);

  hipMemsetAsync(zf, 0, (size_t)2 * NT * 512 * 4, stream);
  hipMemsetAsync(zi, 0, (size_t)(MBLK + SBLK + NW3) * 4, stream);

  token_prep<<<8, 256, 0, stream>>>(coords, bid, sbid, wid, ibid, cnt, selcnt, wincnt);
  scan_all<<<1, 1024, 0, stream>>>(cnt, occ, inv, nocc, selcnt, seloff, selpos,
                                   wincnt, winoff, winpos);
  scatter<<<8, 256, 0, stream>>>(sbid, wid, selpos, winpos, sellist, winlist);

  dim3 gg(32, 8);
  gemm512<<<gg, 256, 0, stream>>>(feats, Wq, q, nullptr, NT);
  gemm512<<<gg, 256, 0, stream>>>(feats, Wk, kf, nullptr, NT);
  gemm512<<<gg, 256, 0, stream>>>(feats, Wv, vf, nullptr, NT);
  gatek<<<24, 256, 0, stream>>>(feats, Wg, gates);

  accum<<<NT, 256, 0, stream>>>(kf, vf, pe, bid, ibid, inv, ckbar, cvbar);
  divide_means<<<4096, 256, 0, stream>>>(ckbar, cvbar, occ, cnt, nocc, sid_key);
  gemm512<<<gg, 256, 0, stream>>>(ckbar, Wck, ckc, nocc, 0);
  gemm512<<<gg, 256, 0, stream>>>(cvbar, Wcv, cvc, nocc, 0);
  transp<<<dim3(32, 8), 256, 0, stream>>>(ckc, ckT, nocc);

  clse<<<dim3(256, 2), 1024, 0, stream>>>(q, ckT, nocc, lpart);
  cpv<<<dim3(256, 2), 1024, 0, stream>>>(q, ckT, cvc, sid_key, nocc, lpart,
                                         selsc_h, opart);
  cfin<<<NT, 64, 0, stream>>>(opart, selsc_h, gates, fused, topk);

  selwin<<<NT, 64, 0, stream>>>(q, kf, vf, topk, seloff, sellist, winoff, winlist,
                                wid, gates, fused);
  gemm512<<<gg, 256, 0, stream>>>(fused, Wo, out, nullptr, NT);
}